// Round 5
// baseline (71.616 us; speedup 1.0000x reference)
//
#include <hip/hip_runtime.h>

// ---------------------------------------------------------------------------
// TreeEncoder fused MFMA kernel, round 5.
//   vs round 4 (71.5 us, MFMA-busy ~11us == floor, activation-pipe-bound):
//   - log2(e) folded into gate weights/biases at prep: MFMA logits are
//     exp2-ready (Wi,Wo scaled by -1.4427, Wc by +2.8854).
//   - merged-rcp activation algebra + Pade[5/4] tanh for the inner tanh
//     (|c|<1 strictly; err <= 5e-8): 8 TRANS -> 5, ~22 VALU -> ~18 per elem.
//   - LDS 61.4 KB -> 47.1 KB (single-buffered weight stage + redbuf union)
//     => 3 blocks/CU instead of 2.  Barrier order per t:
//     MFMA(t) -> bar -> stage-write(t+1) -> bar -> act(t) [reg-only, can
//     overlap with MFMA(t+1) in the scheduler].
//   - embedding B-frags read directly from L2 (16 KB, single use).
// ---------------------------------------------------------------------------

typedef short bf16x8 __attribute__((ext_vector_type(8)));
typedef float f32x4  __attribute__((ext_vector_type(4)));

#define MFMA16(a, b, c) __builtin_amdgcn_mfma_f32_16x16x32_bf16((a), (b), (c), 0, 0, 0)

#define NEG_L2E (-1.44269504088896f)
#define TWO_L2E (2.88539008177793f)

__device__ __forceinline__ unsigned short f2bf(float f) {
    return (unsigned short)((__float_as_uint(f) + 0x8000u) >> 16);
}
__device__ __forceinline__ float frcp(float x)  { return __builtin_amdgcn_rcpf(x); }
__device__ __forceinline__ float fexp2(float x) { return __builtin_amdgcn_exp2f(x); }

// ---------------------------------------------------------------------------
// Prep: weights -> MFMA B-fragment bf16 layout in ws, WITH exp2 prescale.
//   B-frag (16x16x32): lane l holds B[k][n], n = 16*t + (l&15),
//   k = 32*kk + 8*(l>>4) + e.  1KB blocks: [block][lane][16B].
//   ws map (bytes):
//     [0, 16384)       emb_W: block = t*2 + kk            (unscaled)
//     [16384, 212992)  gates: block = (layer*8 + t)*12 + gate*4 + kk
//        gate 0 (Wi): * -1.4427   gate 1 (Wo): * -1.4427  gate 2 (Wc): * 2.8854
// ---------------------------------------------------------------------------
__global__ void prep_frags(const float* __restrict__ embW,
                           const float* __restrict__ Wi,
                           const float* __restrict__ Wo,
                           const float* __restrict__ Wc,
                           char* __restrict__ ws) {
    int fb = blockIdx.x;          // 0..207
    int l  = threadIdx.x;         // 0..63
    int g  = l >> 4, c0 = l & 15;

    const float* src;
    int t, kk;
    size_t dst;
    float scale;
    if (fb < 16) {
        t = fb >> 1; kk = fb & 1;
        src = embW;                                   // [64][128]
        dst = (size_t)fb * 1024;
        scale = 1.0f;
    } else {
        int r = fb - 16;                              // (layer*8+t)*12+gate*4+kk
        int layer = r / 96;
        int r2 = r % 96;
        t = r2 / 12;
        int r3 = r2 % 12;
        int gate = r3 >> 2;
        kk = r3 & 3;
        const float* Ws[3] = {Wi, Wo, Wc};
        src = Ws[gate] + (size_t)layer * 128 * 128;   // [128][128]
        dst = 16384 + (size_t)r * 1024;
        scale = (gate == 2) ? TWO_L2E : NEG_L2E;
    }

    bf16x8 v;
#pragma unroll
    for (int e = 0; e < 8; ++e) {
        int k   = kk * 32 + g * 8 + e;
        int col = t * 16 + c0;
        v[e] = (short)f2bf(scale * src[(size_t)k * 128 + col]);
    }
    *reinterpret_cast<bf16x8*>(ws + dst + (size_t)l * 16) = v;
}

// ---------------------------------------------------------------------------
// Main fused kernel: 1024 blocks x 256 threads; each wave owns 32 rows.
// ---------------------------------------------------------------------------
__global__ __launch_bounds__(256) void tree_enc(
        const float* __restrict__ X,       // [131072][64]
        const float* __restrict__ emb_b,   // [128]
        const float* __restrict__ bWi, const float* __restrict__ bUi,
        const float* __restrict__ bWo, const float* __restrict__ bUo,
        const float* __restrict__ bWc, const float* __restrict__ bUc,
        const char*  __restrict__ frags,   // ws
        float* __restrict__ out) {         // [256][128]

    // 34816 B transpose buffer + 12288 B weight stage (redbuf overlays) = 47104 B
    __shared__ __align__(16) unsigned short hbuf[4][32][136];
    __shared__ __align__(16) char sbuf[12288];

    const int tid = threadIdx.x;
    const int w   = tid >> 6;
    const int l   = tid & 63;
    const int g   = l >> 4;           // k-group
    const int c0  = l & 15;           // col within 16-tile / A row
    const int rowbase = blockIdx.x * 128 + w * 32;
    const int b  = blockIdx.x >> 2;   // 4 blocks per batch

    // ---------------- embedding: h0 = X @ embW + emb_b ----------------
    // (B-frags straight from L2: 16 KB, used once per wave)
    {
        bf16x8 afr[2][2];             // [mtile][kk], K=64
#pragma unroll
        for (int mi = 0; mi < 2; ++mi) {
#pragma unroll
            for (int kk = 0; kk < 2; ++kk) {
                int row = rowbase + mi * 16 + c0;
                const float4* p = reinterpret_cast<const float4*>(
                        X + (size_t)row * 64 + kk * 32 + g * 8);
                float4 v0 = p[0], v1 = p[1];
                bf16x8 a;
                a[0] = (short)f2bf(v0.x); a[1] = (short)f2bf(v0.y);
                a[2] = (short)f2bf(v0.z); a[3] = (short)f2bf(v0.w);
                a[4] = (short)f2bf(v1.x); a[5] = (short)f2bf(v1.y);
                a[6] = (short)f2bf(v1.z); a[7] = (short)f2bf(v1.w);
                afr[mi][kk] = a;
            }
        }
        const f32x4 z4 = {0.f, 0.f, 0.f, 0.f};
#pragma unroll
        for (int t = 0; t < 8; ++t) {
            f32x4 acc[2] = {z4, z4};
#pragma unroll
            for (int kk = 0; kk < 2; ++kk) {
                bf16x8 bf = *reinterpret_cast<const bf16x8*>(
                        frags + ((size_t)(t * 2 + kk) * 64 + l) * 16);
#pragma unroll
                for (int mi = 0; mi < 2; ++mi)
                    acc[mi] = MFMA16(afr[mi][kk], bf, acc[mi]);
            }
            float bias = emb_b[t * 16 + c0];
#pragma unroll
            for (int mi = 0; mi < 2; ++mi)
#pragma unroll
                for (int r = 0; r < 4; ++r)
                    hbuf[w][mi * 16 + g * 4 + r][t * 16 + c0] =
                        f2bf(acc[mi][r] + bias);   // C layout: col=l&15, row=4*(l>>4)+r
        }
    }

    // ---------------- 2 TreeLSTM layers ----------------
    float msum[8];
#pragma unroll
    for (int t = 0; t < 8; ++t) msum[t] = 0.f;

    const f32x4 z4 = {0.f, 0.f, 0.f, 0.f};
#pragma unroll
    for (int layer = 0; layer < 2; ++layer) {
        // A-fragments of h from LDS (wave-private slice; DS in-order per wave)
        bf16x8 A[2][4];
#pragma unroll
        for (int mi = 0; mi < 2; ++mi)
#pragma unroll
            for (int kk = 0; kk < 4; ++kk)
                A[mi][kk] = *reinterpret_cast<const bf16x8*>(
                        &hbuf[w][mi * 16 + c0][kk * 32 + g * 8]);

        const char* fW = frags + 16384 + (size_t)layer * 98304;
        const int bofs = layer * 128;

        // prologue: stage t=0 fragment set (12 KB) into sbuf
        // (layer 1: prior sbuf reads were fenced by t=7's post-MFMA barrier)
        {
            bf16x8 v[3];
#pragma unroll
            for (int i = 0; i < 3; ++i)
                v[i] = *reinterpret_cast<const bf16x8*>(fW + i * 4096 + tid * 16);
#pragma unroll
            for (int i = 0; i < 3; ++i)
                *reinterpret_cast<bf16x8*>(&sbuf[0] + i * 4096 + tid * 16) = v[i];
        }
        __syncthreads();

#pragma unroll
        for (int t = 0; t < 8; ++t) {
            // issue-early: next t's fragment loads (global -> regs)
            bf16x8 pre[3];
            if (t < 7) {
                const char* srcW = fW + (size_t)(t + 1) * 12288;
#pragma unroll
                for (int i = 0; i < 3; ++i)
                    pre[i] = *reinterpret_cast<const bf16x8*>(srcW + i * 4096 + tid * 16);
            }

            // -------- MFMA phase (reads sbuf) --------
            const char* ft = &sbuf[0] + (size_t)l * 16;
            f32x4 ai[2] = {z4, z4};
            f32x4 ao[2] = {z4, z4};
            f32x4 ac[2] = {z4, z4};
#pragma unroll
            for (int kk = 0; kk < 4; ++kk) {
                bf16x8 bi = *reinterpret_cast<const bf16x8*>(ft + (size_t)(0 + kk) * 1024);
                bf16x8 bo = *reinterpret_cast<const bf16x8*>(ft + (size_t)(4 + kk) * 1024);
                bf16x8 bc = *reinterpret_cast<const bf16x8*>(ft + (size_t)(8 + kk) * 1024);
#pragma unroll
                for (int mi = 0; mi < 2; ++mi) {
                    ai[mi] = MFMA16(A[mi][kk], bi, ai[mi]);
                    ao[mi] = MFMA16(A[mi][kk], bo, ao[mi]);
                    ac[mi] = MFMA16(A[mi][kk], bc, ac[mi]);
                }
            }
            __syncthreads();    // all waves done reading sbuf for t

            // -------- stage write (t+1) --------
            if (t < 7) {
#pragma unroll
                for (int i = 0; i < 3; ++i)
                    *reinterpret_cast<bf16x8*>(&sbuf[0] + i * 4096 + tid * 16) = pre[i];
                __syncthreads();   // writes visible before t+1 MFMAs
            }

            // -------- activation phase (registers only; scheduler may
            //          interleave with next iteration's MFMAs) --------
            const int c = t * 16 + c0;
            const float Bi = NEG_L2E * (bWi[bofs + c] + bUi[bofs + c]);
            const float Bo = NEG_L2E * (bWo[bofs + c] + bUo[bofs + c]);
            const float Bc = TWO_L2E * (bWc[bofs + c] + bUc[bofs + c]);
#pragma unroll
            for (int mi = 0; mi < 2; ++mi) {
#pragma unroll
                for (int r = 0; r < 4; ++r) {
                    // ei = e^-xi, eo = e^-xo, u = e^{2 xc}  (scales folded)
                    float ei = fexp2(ai[mi][r] + Bi);
                    float eo = fexp2(ao[mi][r] + Bo);
                    float xc = fminf(ac[mi][r] + Bc, 126.0f);
                    float u  = fexp2(xc);
                    // c = sigmoid(i) * tanh(c~)  -- one rcp for both
                    float cc = (u - 1.0f) * frcp((1.0f + ei) * (u + 1.0f));
                    // h = sigmoid(o) * tanh(c); tanh via Pade[5/4] on |c|<1,
                    // sharing its rcp with sigmoid(o)
                    float u2   = cc * cc;
                    float numx = cc * ((u2 + 105.0f) * u2 + 945.0f);
                    float den  = ((15.0f * u2 + 420.0f) * u2 + 945.0f) * (1.0f + eo);
                    float h    = numx * frcp(den);
                    if (layer == 1) {
                        msum[t] += h;                   // mean partial
                    } else {
                        hbuf[w][mi * 16 + g * 4 + r][c] = f2bf(h);
                    }
                }
            }
        }
    }

    // ---------------- mean over nodes ----------------
    // redbuf overlays sbuf (all sbuf reads fenced by the last post-MFMA barrier)
    float* red = reinterpret_cast<float*>(&sbuf[0]);   // [4][128]
#pragma unroll
    for (int t = 0; t < 8; ++t) {
        float v = msum[t];
        v += __shfl_xor(v, 16);
        v += __shfl_xor(v, 32);
        if (g == 0) red[w * 128 + t * 16 + c0] = v;
    }
    __syncthreads();
    if (tid < 128) {
        float s = red[0 * 128 + tid] + red[1 * 128 + tid] +
                  red[2 * 128 + tid] + red[3 * 128 + tid];
        atomicAdd(&out[b * 128 + tid], s * (1.0f / 512.0f));
    }
}

// ---------------------------------------------------------------------------
extern "C" void kernel_launch(void* const* d_in, const int* in_sizes, int n_in,
                              void* d_out, int out_size, void* d_ws, size_t ws_size,
                              hipStream_t stream) {
    const float* X    = (const float*)d_in[0];
    const float* embW = (const float*)d_in[1];
    const float* embb = (const float*)d_in[2];
    const float* Wi   = (const float*)d_in[3];
    const float* Wo   = (const float*)d_in[4];
    const float* Wc   = (const float*)d_in[5];
    const float* bWi  = (const float*)d_in[6];
    const float* bUi  = (const float*)d_in[7];
    const float* bWo  = (const float*)d_in[8];
    const float* bUo  = (const float*)d_in[9];
    const float* bWc  = (const float*)d_in[10];
    const float* bUc  = (const float*)d_in[11];
    float* out = (float*)d_out;
    char*  ws  = (char*)d_ws;

    hipMemsetAsync(d_out, 0, (size_t)out_size * sizeof(float), stream);
    prep_frags<<<208, 64, 0, stream>>>(embW, Wi, Wo, Wc, ws);
    tree_enc<<<1024, 256, 0, stream>>>(X, embb, bWi, bUi, bWo, bUo, bWc, bUc,
                                       (const char*)ws, out);
}